// Round 3
// baseline (257.276 us; speedup 1.0000x reference)
//
#include <hip/hip_runtime.h>

// Problem constants (fixed by setup_inputs): bs=8, m=4096, T=32, E=65536
#define M      4096
#define TT     32
#define BS     8
#define EE     65536
#define ROWS   64                // rows per workgroup chunk
#define WPR    128               // 32-bit words per row bitmap (M/32)
#define NCHUNK (M / ROWS)        // 64 chunks per batch -> grid = BS*NCHUNK = 512

__global__ void zero_out(float* out) {
    if (threadIdx.x == 0) out[0] = 0.0f;
}

// One workgroup = (batch b, 64-row chunk). Dedup adjacency in a 32 KB LDS
// bitmap, then agg+relu+reduce. No global scratch at all.
// NOTE: harness passes integer inputs as int32 (NOT int64) — reading coo as
// long long* in R1/R2 ran 4 MB past the buffer and aborted the process.
__global__ __launch_bounds__(256) void nil_reg(const float* __restrict__ y,
                                               const int* __restrict__ coo,
                                               float* __restrict__ out) {
    __shared__ unsigned int bm[ROWS * WPR];     // 64 rows x 128 words = 32 KB
    const int tid = threadIdx.x;
    const int b = blockIdx.x / NCHUNK;
    const int chunk = blockIdx.x % NCHUNK;
    const int row0 = chunk * ROWS;

    for (int i = tid; i < ROWS * WPR; i += 256) bm[i] = 0;
    __syncthreads();

    // Phase 1: scan this batch's edges, set bits for sources in our chunk.
    const int* base = coo + (size_t)b * 2 * EE;
    for (int e = tid; e < EE; e += 256) {
        int src = base[e] & (M - 1);            // values already in [0,M)
        int tgt = base[EE + e] & (M - 1);
        int r = src - row0;
        if ((unsigned)r < (unsigned)ROWS)
            atomicOr(&bm[r * WPR + (tgt >> 5)], 1u << (tgt & 31));
    }
    __syncthreads();

    // Phase 2: lane t of each 32-lane group handles column t of one row.
    const float* yb = y + (size_t)b * M * TT;   // batch slice (M, TT)
    const int t = tid & 31;
    const int g = tid >> 5;                     // 8 groups per block
    float total = 0.0f;

    for (int r = g; r < ROWS; r += 8) {
        int i = row0 + r;
        float acc = yb[i * TT + t];             // identity (eye) term
        float ynext = (t < 31) ? yb[i * TT + t + 1] : 0.0f;
        const uint4* rw = (const uint4*)&bm[r * WPR];
        for (int w4 = 0; w4 < WPR / 4; ++w4) {
            uint4 bw = rw[w4];                  // LDS broadcast (same addr per group)
            int jb = w4 * 128;
            unsigned int w;
            w = bw.x; while (w) { int j = __ffs(w) - 1; w &= w - 1; acc += yb[(jb +      j) * TT + t]; }
            w = bw.y; while (w) { int j = __ffs(w) - 1; w &= w - 1; acc += yb[(jb + 32 + j) * TT + t]; }
            w = bw.z; while (w) { int j = __ffs(w) - 1; w &= w - 1; acc += yb[(jb + 64 + j) * TT + t]; }
            w = bw.w; while (w) { int j = __ffs(w) - 1; w &= w - 1; acc += yb[(jb + 96 + j) * TT + t]; }
        }
        if (t < 31) total += fmaxf(ynext - acc, 0.0f);
    }

    // Wave reduce (64 lanes), one atomic per wave (4 per block).
    #pragma unroll
    for (int off = 32; off; off >>= 1) total += __shfl_down(total, off, 64);
    if ((tid & 63) == 0) atomicAdd(out, total);
}

extern "C" void kernel_launch(void* const* d_in, const int* in_sizes, int n_in,
                              void* d_out, int out_size, void* d_ws, size_t ws_size,
                              hipStream_t stream) {
    const float* y = (const float*)d_in[0];     // (BS*M, TT) f32
    const int* coo = (const int*)d_in[1];       // (BS, 2, EE) delivered as int32
    float* out = (float*)d_out;

    zero_out<<<1, 64, 0, stream>>>(out);
    nil_reg<<<BS * NCHUNK, 256, 0, stream>>>(y, coo, out);
}

// Round 4
// 155.263 us; speedup vs baseline: 1.6570x; 1.6570x over previous
//
#include <hip/hip_runtime.h>

// Problem constants (fixed by setup_inputs): bs=8, m=4096, T=32, E=65536
#define M      4096
#define TT     32
#define BS     8
#define EE     65536
#define WPR    128                    // 32-bit words per adjacency row (M/32)
#define WPB    (M * WPR)              // words per batch bit-matrix (2 MB)
#define BITS_BYTES ((size_t)BS * WPB * 4)   // 16 MB

// ---------------- Fast path (global bit-matrix in d_ws) ----------------

// One edge pass: exact dedup via atomicOr into the global bit matrix.
__global__ __launch_bounds__(256) void build_adj(const int* __restrict__ coo,
                                                 unsigned int* __restrict__ bits) {
    int idx = blockIdx.x * 256 + threadIdx.x;          // [0, BS*EE/4)
    int b = idx >> 14;                                 // 16384 int4-groups per batch
    int e4 = idx & 16383;
    const int* base = coo + (size_t)b * 2 * EE;
    int4 s = ((const int4*)base)[e4];
    int4 g = ((const int4*)(base + EE))[e4];
    unsigned int* bb = bits + (size_t)b * WPB;
    atomicOr(&bb[(s.x & (M - 1)) * WPR + ((g.x & (M - 1)) >> 5)], 1u << (g.x & 31));
    atomicOr(&bb[(s.y & (M - 1)) * WPR + ((g.y & (M - 1)) >> 5)], 1u << (g.y & 31));
    atomicOr(&bb[(s.z & (M - 1)) * WPR + ((g.z & (M - 1)) >> 5)], 1u << (g.z & 31));
    atomicOr(&bb[(s.w & (M - 1)) * WPR + ((g.w & (M - 1)) >> 5)], 1u << (g.w & 31));
}

// One 32-lane group per row (lane = t). No LDS bitmap -> high occupancy.
// Bitmap quads software-pipelined to break the load->branch chain.
__global__ __launch_bounds__(256) void compute_reg(const float* __restrict__ y,
                                                   const unsigned int* __restrict__ bits,
                                                   float* __restrict__ out) {
    const int tid = threadIdx.x;
    const int t = tid & 31;
    const int g = tid >> 5;                            // 8 groups/block
    const int row = blockIdx.x * 8 + g;                // [0, BS*M)
    const int b = row >> 12;
    const int i = row & (M - 1);

    const float* yb = y + (size_t)b * M * TT;
    const uint4* rw = (const uint4*)(bits + (size_t)b * WPB + (size_t)i * WPR);

    float acc = yb[i * TT + t];                        // identity (eye) term
    float ynext = (t < 31) ? yb[i * TT + t + 1] : 0.0f;

    uint4 cur = rw[0];
    #pragma unroll 1
    for (int q = 0; q < 32; ++q) {
        uint4 nxt;
        if (q < 31) nxt = rw[q + 1];                   // prefetch while processing cur
        else { nxt.x = nxt.y = nxt.z = nxt.w = 0u; }
        int jb = q << 7;
        unsigned int w;
        w = cur.x; while (w) { int j = __ffs(w) - 1; w &= w - 1; acc += yb[(jb +      j) * TT + t]; }
        w = cur.y; while (w) { int j = __ffs(w) - 1; w &= w - 1; acc += yb[(jb + 32 + j) * TT + t]; }
        w = cur.z; while (w) { int j = __ffs(w) - 1; w &= w - 1; acc += yb[(jb + 64 + j) * TT + t]; }
        w = cur.w; while (w) { int j = __ffs(w) - 1; w &= w - 1; acc += yb[(jb + 96 + j) * TT + t]; }
        cur = nxt;
    }

    float v = (t < 31) ? fmaxf(ynext - acc, 0.0f) : 0.0f;
    #pragma unroll
    for (int off = 32; off; off >>= 1) v += __shfl_down(v, off, 64);

    __shared__ float wsum[4];
    if ((tid & 63) == 0) wsum[tid >> 6] = v;
    __syncthreads();
    if (tid == 0) atomicAdd(out, wsum[0] + wsum[1] + wsum[2] + wsum[3]);
}

// ---------------- Fallback path (R3: LDS bitmap, no scratch) ----------------
#define ROWS   64
#define NCHUNK (M / ROWS)

__global__ __launch_bounds__(256) void nil_reg_lds(const float* __restrict__ y,
                                                   const int* __restrict__ coo,
                                                   float* __restrict__ out) {
    __shared__ unsigned int bm[ROWS * WPR];
    const int tid = threadIdx.x;
    const int b = blockIdx.x / NCHUNK;
    const int chunk = blockIdx.x % NCHUNK;
    const int row0 = chunk * ROWS;

    for (int i = tid; i < ROWS * WPR; i += 256) bm[i] = 0;
    __syncthreads();

    const int* base = coo + (size_t)b * 2 * EE;
    for (int e = tid; e < EE; e += 256) {
        int src = base[e] & (M - 1);
        int tgt = base[EE + e] & (M - 1);
        int r = src - row0;
        if ((unsigned)r < (unsigned)ROWS)
            atomicOr(&bm[r * WPR + (tgt >> 5)], 1u << (tgt & 31));
    }
    __syncthreads();

    const float* yb = y + (size_t)b * M * TT;
    const int t = tid & 31;
    const int g = tid >> 5;
    float total = 0.0f;

    for (int r = g; r < ROWS; r += 8) {
        int i = row0 + r;
        float acc = yb[i * TT + t];
        float ynext = (t < 31) ? yb[i * TT + t + 1] : 0.0f;
        const uint4* rwp = (const uint4*)&bm[r * WPR];
        for (int w4 = 0; w4 < WPR / 4; ++w4) {
            uint4 bw = rwp[w4];
            int jb = w4 * 128;
            unsigned int w;
            w = bw.x; while (w) { int j = __ffs(w) - 1; w &= w - 1; acc += yb[(jb +      j) * TT + t]; }
            w = bw.y; while (w) { int j = __ffs(w) - 1; w &= w - 1; acc += yb[(jb + 32 + j) * TT + t]; }
            w = bw.z; while (w) { int j = __ffs(w) - 1; w &= w - 1; acc += yb[(jb + 64 + j) * TT + t]; }
            w = bw.w; while (w) { int j = __ffs(w) - 1; w &= w - 1; acc += yb[(jb + 96 + j) * TT + t]; }
        }
        if (t < 31) total += fmaxf(ynext - acc, 0.0f);
    }

    #pragma unroll
    for (int off = 32; off; off >>= 1) total += __shfl_down(total, off, 64);
    if ((tid & 63) == 0) atomicAdd(out, total);
}

extern "C" void kernel_launch(void* const* d_in, const int* in_sizes, int n_in,
                              void* d_out, int out_size, void* d_ws, size_t ws_size,
                              hipStream_t stream) {
    const float* y = (const float*)d_in[0];     // (BS*M, TT) f32
    const int* coo = (const int*)d_in[1];       // (BS, 2, EE) delivered as int32
    float* out = (float*)d_out;

    hipMemsetAsync(out, 0, sizeof(float), stream);

    if (ws_size >= BITS_BYTES) {
        unsigned int* bits = (unsigned int*)d_ws;
        hipMemsetAsync(bits, 0, BITS_BYTES, stream);
        build_adj<<<(BS * EE / 4) / 256, 256, 0, stream>>>(coo, bits);
        compute_reg<<<(BS * M) / 8, 256, 0, stream>>>(y, bits, out);
    } else {
        nil_reg_lds<<<BS * NCHUNK, 256, 0, stream>>>(y, coo, out);
    }
}